// Round 5
// baseline (490.825 us; speedup 1.0000x reference)
//
#include <hip/hip_runtime.h>

typedef __attribute__((ext_vector_type(4))) float f32x4;
typedef __attribute__((ext_vector_type(8))) _Float16 f16x8;

#define D 256          // D_in == D_out == 256
#define VBS 128        // ghost batch rows per chunk
#define BN_EPS 1e-5f

// Pack W[k][n] (f32, row-major 256x256) into f16 MFMA fragment order.
// Used as the A-operand (A = W^T tile: A[m=out-col][k]); A-frag layout
// m=lane&15, k=(lane>>4)*8+j gives wp value W[kb*32+(l>>4)*8+j][ct*16+(l&15)].
__global__ void pack_w_kernel(const float* __restrict__ W, _Float16* __restrict__ wp) {
    int idx = blockIdx.x * blockDim.x + threadIdx.x;   // [0, 8192)
    int kb  = idx >> 10;          // 8 k-blocks of 32
    int rem = idx & 1023;
    int ct  = rem >> 6;           // 16 col-tiles of 16
    int l   = rem & 63;           // lane
    int col = ct * 16 + (l & 15);
    int k0  = kb * 32 + ((l >> 4) << 3);
    f16x8 v;
#pragma unroll
    for (int j = 0; j < 8; ++j) v[j] = (_Float16)W[(k0 + j) * D + col];
    *reinterpret_cast<f16x8*>(wp + (size_t)idx * 8) = v;
}

// 16-lane (DPP row) all-lanes sum: 4 x v_add_f32 with row_ror, VALU pipe only.
template <int CTRL>
__device__ __forceinline__ float row_ror_add(float x) {
    int v = __builtin_amdgcn_update_dpp(0, __builtin_bit_cast(int, x),
                                        CTRL, 0xF, 0xF, true);
    return x + __builtin_bit_cast(float, v);
}
__device__ __forceinline__ float rsum16(float x) {
    x = row_ror_add<0x128>(x);   // += ror 8
    x = row_ror_add<0x124>(x);   // += ror 4
    x = row_ror_add<0x122>(x);   // += ror 2
    x = row_ror_add<0x121>(x);   // += ror 1  -> all 16 lanes hold the sum
    return x;
}

// One block per BN chunk of 128 rows; 4 waves x 32 rows (two 16-row strips).
// TRANSPOSED mfma: acc[st][ct] = mfma(W^T-frag, a-frag) -> h^T fragment:
//   lane holds row (strip_row0 + lane&15), cols ct*16 + (lane>>4)*4 + {0..3}.
__global__ __launch_bounds__(256, 2)
void fused_kernel(const float* __restrict__ A, const float* __restrict__ priors,
                  const _Float16* __restrict__ Wp, const float* __restrict__ gamma,
                  const float* __restrict__ beta, float* __restrict__ out) {
    const int chunk = blockIdx.x;
    const int tid   = threadIdx.x;
    const int wid   = tid >> 6;    // 0..3
    const int lane  = tid & 63;
    const int lrow  = lane & 15;   // row within a 16-row strip
    const int q     = lane >> 4;   // col-quad group (0..3)

    const int row0 = chunk * VBS + wid * 32 + lrow;   // strip 0 row
    const int row1 = row0 + 16;                        // strip 1 row

    f32x4 acc[2][16];
#pragma unroll
    for (int st = 0; st < 2; ++st)
#pragma unroll
        for (int ct = 0; ct < 16; ++ct) {
            f32x4 z = {0.f, 0.f, 0.f, 0.f};
            acc[st][ct] = z;
        }

    const float* a0 = A + (size_t)row0 * D + q * 8;
    const float* a1 = A + (size_t)row1 * D + q * 8;

    // ---- GEMM: h^T = W^T @ a^T (K = 256 in 8 steps of 32) ----
    // unroll 1 + 1-deep a-prefetch: bounded register pressure, no spill.
    f32x4 lo0 = *reinterpret_cast<const f32x4*>(a0);
    f32x4 hi0 = *reinterpret_cast<const f32x4*>(a0 + 4);
    f32x4 lo1 = *reinterpret_cast<const f32x4*>(a1);
    f32x4 hi1 = *reinterpret_cast<const f32x4*>(a1 + 4);
#pragma unroll 1
    for (int kb = 0; kb < 8; ++kb) {
        f32x4 nlo0, nhi0, nlo1, nhi1;
        if (kb < 7) {
            nlo0 = *reinterpret_cast<const f32x4*>(a0 + (kb + 1) * 32);
            nhi0 = *reinterpret_cast<const f32x4*>(a0 + (kb + 1) * 32 + 4);
            nlo1 = *reinterpret_cast<const f32x4*>(a1 + (kb + 1) * 32);
            nhi1 = *reinterpret_cast<const f32x4*>(a1 + (kb + 1) * 32 + 4);
        }
        f16x8 t0, t1;
#pragma unroll
        for (int j = 0; j < 4; ++j) {
            t0[j] = (_Float16)lo0[j]; t0[j + 4] = (_Float16)hi0[j];
            t1[j] = (_Float16)lo1[j]; t1[j + 4] = (_Float16)hi1[j];
        }
        const f16x8* wpp = reinterpret_cast<const f16x8*>(Wp) + kb * 1024 + lane;
        // two half-batches of 8 W-fragments: <=32 regs of W in flight
#pragma unroll
        for (int half = 0; half < 2; ++half) {
            f16x8 wf[8];
#pragma unroll
            for (int c = 0; c < 8; ++c) wf[c] = wpp[(half * 8 + c) * 64];
#pragma unroll
            for (int c = 0; c < 8; ++c) {
                int ct = half * 8 + c;
                acc[0][ct] = __builtin_amdgcn_mfma_f32_16x16x32_f16(wf[c], t0, acc[0][ct], 0, 0, 0);
                acc[1][ct] = __builtin_amdgcn_mfma_f32_16x16x32_f16(wf[c], t1, acc[1][ct], 0, 0, 0);
            }
        }
        lo0 = nlo0; hi0 = nhi0; lo1 = nlo1; hi1 = nhi1;
    }

    // ---- Ghost BN stats: per-column sum/sumsq over 128 rows ----
    // Pre-add the two strips (rows r and r+16), then DPP rsum16 over the
    // 16 lanes of the strip: 512 VALU dpp-adds total, zero DS-pipe ops.
    __shared__ float sSum[4][D];
    __shared__ float sSq[4][D];
#pragma unroll
    for (int ct = 0; ct < 16; ++ct) {
        f32x4 s = acc[0][ct] + acc[1][ct];
        f32x4 qv = acc[0][ct] * acc[0][ct] + acc[1][ct] * acc[1][ct];
#pragma unroll
        for (int c = 0; c < 4; ++c) {
            s[c]  = rsum16(s[c]);
            qv[c] = rsum16(qv[c]);
        }
        if (lrow == 0) {
            *reinterpret_cast<f32x4*>(&sSum[wid][ct * 16 + q * 4]) = s;
            *reinterpret_cast<f32x4*>(&sSq [wid][ct * 16 + q * 4]) = qv;
        }
    }
    __syncthreads();

    __shared__ float sA[D], sB[D];   // per-column: a = gamma*rstd, b = beta - mean*a
    {
        const int c = tid;   // exactly 256 threads, one column each
        float s  = sSum[0][c] + sSum[1][c] + sSum[2][c] + sSum[3][c];
        float qq = sSq[0][c] + sSq[1][c] + sSq[2][c] + sSq[3][c];
        float mean = s * (1.0f / 128.0f);
        float var  = qq * (1.0f / 128.0f) - mean * mean;
        float g    = gamma[c] * rsqrtf(var + BN_EPS);
        sA[c] = g;
        sB[c] = beta[c] - mean * g;
    }
    __syncthreads();

    // ---- epilogue: BN apply, * priors, sparsemax (one row/lane per strip) ----
    const float* pr0 = priors + (size_t)row0 * D;
    const float* pr1 = priors + (size_t)row1 * D;
    float m0 = -1e30f, m1 = -1e30f;
#pragma unroll 2
    for (int ct = 0; ct < 16; ++ct) {
        int c0 = ct * 16 + q * 4;
        f32x4 ga = *reinterpret_cast<const f32x4*>(&sA[c0]);
        f32x4 bb = *reinterpret_cast<const f32x4*>(&sB[c0]);
        f32x4 p0 = *reinterpret_cast<const f32x4*>(&pr0[c0]);
        f32x4 p1 = *reinterpret_cast<const f32x4*>(&pr1[c0]);
        f32x4 x0 = (acc[0][ct] * ga + bb) * p0;
        f32x4 x1 = (acc[1][ct] * ga + bb) * p1;
        acc[0][ct] = x0;
        acc[1][ct] = x1;
        m0 = fmaxf(m0, fmaxf(fmaxf(x0[0], x0[1]), fmaxf(x0[2], x0[3])));
        m1 = fmaxf(m1, fmaxf(fmaxf(x1[0], x1[1]), fmaxf(x1[2], x1[3])));
    }
    m0 = fmaxf(m0, __shfl_xor(m0, 16)); m1 = fmaxf(m1, __shfl_xor(m1, 16));
    m0 = fmaxf(m0, __shfl_xor(m0, 32)); m1 = fmaxf(m1, __shfl_xor(m1, 32));

    // Michelot fixed-point, max-shift folded into tau0 = m - 1:
    // tau' = (sum_{x>tau} x - 1)/#{x>tau}, monotone non-decreasing to tau*.
    float t0 = m0 - 1.0f, t1 = m1 - 1.0f;
#pragma unroll 1
    for (int it = 0; it < 32; ++it) {
        float s0 = 0.f, c0 = 0.f, s1 = 0.f, c1 = 0.f;
#pragma unroll
        for (int ct = 0; ct < 16; ++ct) {
#pragma unroll
            for (int k = 0; k < 4; ++k) {
                float z0 = acc[0][ct][k], z1 = acc[1][ct][k];
                if (z0 > t0) { s0 += z0; c0 += 1.f; }
                if (z1 > t1) { s1 += z1; c1 += 1.f; }
            }
        }
        s0 += __shfl_xor(s0, 16); c0 += __shfl_xor(c0, 16);
        s1 += __shfl_xor(s1, 16); c1 += __shfl_xor(c1, 16);
        s0 += __shfl_xor(s0, 32); c0 += __shfl_xor(c0, 32);
        s1 += __shfl_xor(s1, 32); c1 += __shfl_xor(c1, 32);
        float n0 = (s0 - 1.0f) / c0;
        float n1 = (s1 - 1.0f) / c1;
        bool done = (n0 <= t0) & (n1 <= t1);
        t0 = fmaxf(t0, n0);
        t1 = fmaxf(t1, n1);
        if (__all(done)) break;
    }

    float* ob0 = out + (size_t)row0 * D;
    float* ob1 = out + (size_t)row1 * D;
#pragma unroll 2
    for (int ct = 0; ct < 16; ++ct) {
        int c0 = ct * 16 + q * 4;
        f32x4 x0 = acc[0][ct], x1 = acc[1][ct];
        f32x4 r0, r1;
#pragma unroll
        for (int k = 0; k < 4; ++k) {
            r0[k] = fmaxf(x0[k] - t0, 0.f);
            r1[k] = fmaxf(x1[k] - t1, 0.f);
        }
        *reinterpret_cast<f32x4*>(&ob0[c0]) = r0;
        *reinterpret_cast<f32x4*>(&ob1[c0]) = r1;
    }
}

extern "C" void kernel_launch(void* const* d_in, const int* in_sizes, int n_in,
                              void* d_out, int out_size, void* d_ws, size_t ws_size,
                              hipStream_t stream) {
    const float* a      = (const float*)d_in[0];
    const float* priors = (const float*)d_in[1];
    const float* W      = (const float*)d_in[2];
    // d_in[3] = b : unused — ghost-BN mean subtraction cancels any per-column bias.
    const float* gamma  = (const float*)d_in[4];
    const float* beta   = (const float*)d_in[5];
    float* out = (float*)d_out;
    _Float16* wp = (_Float16*)d_ws;   // 256*256 f16 = 128 KB packed W

    const int B = in_sizes[0] / D;        // 262144
    const int nchunks = B / VBS;          // 2048

    hipLaunchKernelGGL(pack_w_kernel, dim3(32), dim3(256), 0, stream, W, wp);
    hipLaunchKernelGGL(fused_kernel, dim3(nchunks), dim3(256), 0, stream,
                       a, priors, wp, gamma, beta, out);
}

// Round 6
// 240.796 us; speedup vs baseline: 2.0383x; 2.0383x over previous
//
#include <hip/hip_runtime.h>

typedef __attribute__((ext_vector_type(4))) float f32x4;
typedef __attribute__((ext_vector_type(8))) _Float16 f16x8;

#define D 256          // D_in == D_out == 256
#define VBS 128        // ghost batch rows per chunk
#define BN_EPS 1e-5f

// Pack W[k][n] (f32, row-major 256x256) into f16 MFMA fragment order.
// Used as the A-operand (A = W^T tile); frag value = W[kb*32+(l>>4)*8+j][ct*16+(l&15)].
__global__ void pack_w_kernel(const float* __restrict__ W, _Float16* __restrict__ wp) {
    int idx = blockIdx.x * blockDim.x + threadIdx.x;   // [0, 8192)
    int kb  = idx >> 10;          // 8 k-blocks of 32
    int rem = idx & 1023;
    int ct  = rem >> 6;           // 16 col-tiles of 16
    int l   = rem & 63;           // lane
    int col = ct * 16 + (l & 15);
    int k0  = kb * 32 + ((l >> 4) << 3);
    f16x8 v;
#pragma unroll
    for (int j = 0; j < 8; ++j) v[j] = (_Float16)W[(k0 + j) * D + col];
    *reinterpret_cast<f16x8*>(wp + (size_t)idx * 8) = v;
}

// 16-lane (DPP row) all-lanes sum: 4 x v_add_f32 with row_ror, VALU pipe only.
template <int CTRL>
__device__ __forceinline__ float row_ror_add(float x) {
    int v = __builtin_amdgcn_update_dpp(0, __builtin_bit_cast(int, x),
                                        CTRL, 0xF, 0xF, true);
    return x + __builtin_bit_cast(float, v);
}
__device__ __forceinline__ float rsum16(float x) {
    x = row_ror_add<0x128>(x);   // += ror 8
    x = row_ror_add<0x124>(x);   // += ror 4
    x = row_ror_add<0x122>(x);   // += ror 2
    x = row_ror_add<0x121>(x);   // += ror 1
    return x;
}

// One block per BN chunk of 128 rows; 8 waves x 16 rows (ONE strip per wave).
// TRANSPOSED mfma: acc[ct] = mfma(W^T-frag, a-frag) -> h^T fragment:
//   lane holds row (chunk*128 + wid*16 + lane&15), cols ct*16 + (lane>>4)*4 + {0..3}.
// acc[16] = 64 VGPR/thread; peak pressure ~105 -> fits 128-reg cap -> 2 blocks/CU.
__global__ __launch_bounds__(512, 4)
void fused_kernel(const float* __restrict__ A, const float* __restrict__ priors,
                  const _Float16* __restrict__ Wp, const float* __restrict__ gamma,
                  const float* __restrict__ beta, float* __restrict__ out) {
    const int tid  = threadIdx.x;
    const int wid  = tid >> 6;    // 0..7
    const int lane = tid & 63;
    const int lrow = lane & 15;   // row within the wave's 16-row strip
    const int q    = lane >> 4;   // col-quad group (0..3)

    const int myrow = blockIdx.x * VBS + wid * 16 + lrow;

    f32x4 acc[16];
#pragma unroll
    for (int ct = 0; ct < 16; ++ct) {
        f32x4 z = {0.f, 0.f, 0.f, 0.f};
        acc[ct] = z;
    }

    const float* a0 = A + (size_t)myrow * D + q * 8;

    // ---- GEMM: h^T = W^T @ a^T (K = 256 in 8 steps of 32) ----
    // 1-deep a-prefetch, W in batches of 4: peak regs = acc64+a8+t4+W16+misc.
    f32x4 lo = *reinterpret_cast<const f32x4*>(a0);
    f32x4 hi = *reinterpret_cast<const f32x4*>(a0 + 4);
#pragma unroll 1
    for (int kb = 0; kb < 8; ++kb) {
        f16x8 t;
#pragma unroll
        for (int j = 0; j < 4; ++j) { t[j] = (_Float16)lo[j]; t[j + 4] = (_Float16)hi[j]; }
        if (kb < 7) {   // overwrite a-regs right after conversion
            lo = *reinterpret_cast<const f32x4*>(a0 + (kb + 1) * 32);
            hi = *reinterpret_cast<const f32x4*>(a0 + (kb + 1) * 32 + 4);
        }
        const f16x8* wpp = reinterpret_cast<const f16x8*>(Wp) + kb * 1024 + lane;
#pragma unroll
        for (int g = 0; g < 4; ++g) {
            f16x8 w0 = wpp[(g * 4 + 0) * 64];
            f16x8 w1 = wpp[(g * 4 + 1) * 64];
            f16x8 w2 = wpp[(g * 4 + 2) * 64];
            f16x8 w3 = wpp[(g * 4 + 3) * 64];
            acc[g * 4 + 0] = __builtin_amdgcn_mfma_f32_16x16x32_f16(w0, t, acc[g * 4 + 0], 0, 0, 0);
            acc[g * 4 + 1] = __builtin_amdgcn_mfma_f32_16x16x32_f16(w1, t, acc[g * 4 + 1], 0, 0, 0);
            acc[g * 4 + 2] = __builtin_amdgcn_mfma_f32_16x16x32_f16(w2, t, acc[g * 4 + 2], 0, 0, 0);
            acc[g * 4 + 3] = __builtin_amdgcn_mfma_f32_16x16x32_f16(w3, t, acc[g * 4 + 3], 0, 0, 0);
        }
    }

    // ---- priors prefetch (independent of stats): hide HBM latency under barriers
    const float* pr = priors + (size_t)myrow * D;
    f32x4 pp[8];
#pragma unroll
    for (int ct = 0; ct < 8; ++ct)
        pp[ct] = *reinterpret_cast<const f32x4*>(pr + ct * 16 + q * 4);

    // ---- Ghost BN stats: per-column sum/sumsq over 128 rows (DPP, VALU-only) ----
    __shared__ float sSum[8][D];
    __shared__ float sSq[8][D];
#pragma unroll
    for (int ct = 0; ct < 16; ++ct) {
        f32x4 s = acc[ct];
        f32x4 qv = s * s;
#pragma unroll
        for (int c = 0; c < 4; ++c) { s[c] = rsum16(s[c]); qv[c] = rsum16(qv[c]); }
        if (lrow == 0) {
            *reinterpret_cast<f32x4*>(&sSum[wid][ct * 16 + q * 4]) = s;
            *reinterpret_cast<f32x4*>(&sSq [wid][ct * 16 + q * 4]) = qv;
        }
    }
    __syncthreads();

    __shared__ float sA[D], sB[D];   // per-column: a = gamma*rstd, b = beta - mean*a
    if (tid < D) {
        float s = 0.f, qq = 0.f;
#pragma unroll
        for (int w = 0; w < 8; ++w) { s += sSum[w][tid]; qq += sSq[w][tid]; }
        float mean = s * (1.0f / 128.0f);
        float var  = qq * (1.0f / 128.0f) - mean * mean;
        float g    = gamma[tid] * rsqrtf(var + BN_EPS);
        sA[tid] = g;
        sB[tid] = beta[tid] - mean * g;
    }
    __syncthreads();

    // ---- epilogue: BN apply, * priors, sparsemax (one row per lrow-lane) ----
    float m = -1e30f;
#pragma unroll
    for (int ct = 0; ct < 16; ++ct) {
        int c0 = ct * 16 + q * 4;
        f32x4 ga = *reinterpret_cast<const f32x4*>(&sA[c0]);
        f32x4 bb = *reinterpret_cast<const f32x4*>(&sB[c0]);
        f32x4 p  = (ct < 8) ? pp[ct] : *reinterpret_cast<const f32x4*>(pr + c0);
        f32x4 x  = (acc[ct] * ga + bb) * p;
        acc[ct] = x;
        m = fmaxf(m, fmaxf(fmaxf(x[0], x[1]), fmaxf(x[2], x[3])));
    }
    m = fmaxf(m, __shfl_xor(m, 16));
    m = fmaxf(m, __shfl_xor(m, 32));

    // Michelot fixed-point, max-shift folded into tau0 = m - 1.
    float tau = m - 1.0f;
#pragma unroll 1
    for (int it = 0; it < 32; ++it) {
        float s = 0.f, c = 0.f;
#pragma unroll
        for (int ct = 0; ct < 16; ++ct) {
#pragma unroll
            for (int k = 0; k < 4; ++k) {
                float z = acc[ct][k];
                if (z > tau) { s += z; c += 1.f; }
            }
        }
        s += __shfl_xor(s, 16); c += __shfl_xor(c, 16);
        s += __shfl_xor(s, 32); c += __shfl_xor(c, 32);
        float n = (s - 1.0f) / c;
        bool done = (n <= tau);
        tau = fmaxf(tau, n);
        if (__all(done)) break;
    }

    float* ob = out + (size_t)myrow * D;
#pragma unroll
    for (int ct = 0; ct < 16; ++ct) {
        int c0 = ct * 16 + q * 4;
        f32x4 x = acc[ct];
        f32x4 r;
#pragma unroll
        for (int k = 0; k < 4; ++k) r[k] = fmaxf(x[k] - tau, 0.f);
        __builtin_nontemporal_store(r, reinterpret_cast<f32x4*>(&ob[c0]));
    }
}

extern "C" void kernel_launch(void* const* d_in, const int* in_sizes, int n_in,
                              void* d_out, int out_size, void* d_ws, size_t ws_size,
                              hipStream_t stream) {
    const float* a      = (const float*)d_in[0];
    const float* priors = (const float*)d_in[1];
    const float* W      = (const float*)d_in[2];
    // d_in[3] = b : unused — ghost-BN mean subtraction cancels any per-column bias.
    const float* gamma  = (const float*)d_in[4];
    const float* beta   = (const float*)d_in[5];
    float* out = (float*)d_out;
    _Float16* wp = (_Float16*)d_ws;   // 256*256 f16 = 128 KB packed W

    const int B = in_sizes[0] / D;        // 262144
    const int nchunks = B / VBS;          // 2048

    hipLaunchKernelGGL(pack_w_kernel, dim3(32), dim3(256), 0, stream, W, wp);
    hipLaunchKernelGGL(fused_kernel, dim3(nchunks), dim3(512), 0, stream,
                       a, priors, wp, gamma, beta, out);
}